// Round 14
// baseline (273.561 us; speedup 1.0000x reference)
//
#include <hip/hip_runtime.h>
#include <math.h>

// Problem constants: B=32, T=128, R=9, D=512. 64 pairs (32 pos + 32 neg).
#define BTRD (128*9*512)

typedef _Float16 half8 __attribute__((ext_vector_type(8)));
typedef float f32x4 __attribute__((ext_vector_type(4)));

// ---------------------------------------------------------------------------
// prep: fp32->f16 cvt for P/N (A is consumed as f32 by sim) + weight transforms
// ---------------------------------------------------------------------------
__global__ __launch_bounds__(256) void prep_kernel(
    const float* __restrict__ P, const float* __restrict__ Nn,
    _Float16* __restrict__ Pf, _Float16* __restrict__ Nf,
    const float* __restrict__ w2, const float* __restrict__ w3,
    _Float16* __restrict__ w2t, _Float16* __restrict__ w3t)
{
  int bid = blockIdx.x;
  if (bid < 18432) {
    int which = bid / 9216;
    const float* in = which == 0 ? P : Nn;
    _Float16* out = which == 0 ? Pf : Nf;
    int idx = (bid - which * 9216) * 256 + threadIdx.x;
    const float4* in4 = (const float4*)in;
    float4 a = in4[idx * 2], c = in4[idx * 2 + 1];
    half8 h = { (_Float16)a.x, (_Float16)a.y, (_Float16)a.z, (_Float16)a.w,
                (_Float16)c.x, (_Float16)c.y, (_Float16)c.z, (_Float16)c.w };
    ((half8*)out)[idx] = h;
  } else {
    int idx = (bid - 18432) * 256 + threadIdx.x;
    if (idx < 18432) {
      int tap = idx >> 11, oc = (idx >> 5) & 63, ic = idx & 31;
      w2t[idx] = (_Float16)w2[(oc * 32 + ic) * 9 + tap];
    } else if (idx < 18432 + 73728) {
      int j = idx - 18432;
      int tap = j >> 13, oc = (j >> 6) & 127, ic = j & 63;
      w3t[j] = (_Float16)w3[(oc * 64 + ic) * 9 + tap];
    }
  }
}

// ---------------------------------------------------------------------------
// Stage A (MFMA v11): v7's proven 1-barrier reg-staged pipeline, K-step 64.
// Q LDS holds o in 0..7 only: 128 rows (r = i*8 + o) x 512k f16 = 128KB,
// swizzle slot sp -> sp^(r&7). o=8 A-frags live in 32 VGPRs per og1 lane
// (o8f[16] half8, loaded once from f32 A in prologue; A is p-invariant,
// reused across 9p x 2 tsel). T: 2 parity buffers x 2 kh sub-buffers of
// 8KB, each sub-buffer EXACTLY v7's layout (row 64B, 4 slots, XOR
// (j>>1)&3) -> verified read/write patterns. 128K + 32K = 160KB exactly.
// 72 K64-steps/tsel, ONE lgkmcnt(0)+s_barrier each (half of v7's 144).
// Per step: T_ISSUE set s+3 (2 chunks/thread, counted vmcnt), T_WRITE set
// s+1 (opposite parity - safe: prev barrier drained all reads), then
// kh=0,1: 2 B-reads + A-frags (LDS or o8f regs) + MFMAs.
// 512 thr = 8 waves = 2/SIMD. Wave = (og: o 0..4 / 5..8) x (jq: 32 j).
// Both tsel per block; 256 blocks = 1/CU, XCD-chunked remap.
// ---------------------------------------------------------------------------
template<int O, int OB>
__device__ __forceinline__ void sim_run(
    const float* __restrict__ Q32, const _Float16* __restrict__ TP,
    const _Float16* __restrict__ TN,
    _Float16* __restrict__ lds, int i0, int tid, int jq, int b,
    const float* __restrict__ qm, const float* __restrict__ pm,
    const float* __restrict__ nm, float* __restrict__ simout)
{
  int lane = tid & 63;
  int lrow = lane & 15, lk8 = lane >> 4;

  const float* qb = Q32 + ((size_t)(i0 * 9) << 9);

  // ---- Q prologue: o 0..7 rows -> swizzled LDS (8192 chunks / 512 thr) ----
#pragma unroll
  for (int it = 0; it < 16; it++) {
    int c = it * 512 + tid;
    int r = c >> 6, sp = c & 63;              // r = i*8 + o (o in 0..7)
    const float* src = qb + ((size_t)((r >> 3) * 9 + (r & 7)) << 9) + (sp << 3);
    float4 a = *(const float4*)src;
    float4 cc = *(const float4*)(src + 4);
    half8 h = { (_Float16)a.x, (_Float16)a.y, (_Float16)a.z, (_Float16)a.w,
                (_Float16)cc.x, (_Float16)cc.y, (_Float16)cc.z, (_Float16)cc.w };
    *(half8*)&lds[r * 512 + ((sp ^ (r & 7)) << 3)] = h;
  }

  // ---- o=8 register cache (og1 lanes only): 16 x half8 = 32 VGPR ----
  half8 o8f[16];
  if (OB != 0) {
    const float* o8src = qb + ((size_t)(lrow * 9 + 8) << 9) + (lk8 << 3);
#pragma unroll
    for (int c = 0; c < 16; c++) {
      float4 a = *(const float4*)(o8src + (c << 5));
      float4 cc = *(const float4*)(o8src + (c << 5) + 4);
      o8f[c] = (half8){ (_Float16)a.x, (_Float16)a.y, (_Float16)a.z, (_Float16)a.w,
                        (_Float16)cc.x, (_Float16)cc.y, (_Float16)cc.z, (_Float16)cc.w };
    }
  }
  __syncthreads();

  // per-thread T chunk: row jc = tid>>2, slot spc = tid&3 (within each 8KB
  // kh sub-buffer of 128 rows x 32 f16). Same mapping/swizzle as v7.
  int jc = tid >> 2, spc = tid & 3;
  int ld = jc * 32 + ((spc ^ ((jc >> 1) & 3)) << 3);

  float* ex = (float*)(lds + 65536);
  const float* qmv = qm + b * 128;
  const float inv9 = 1.0f / 9.0f;

  for (int tsel = 0; tsel < 2; ++tsel) {
    const _Float16* tg = (tsel ? TN : TP) + (size_t)jc * 4608 + (spc << 3);

    half8 st[4][2];       // rotating sets x 2 kh chunks, static indices only
    f32x4 acc[O][2], mx[O][2];
#pragma unroll
    for (int oo = 0; oo < O; oo++)
#pragma unroll
      for (int jt = 0; jt < 2; jt++) {
        acc[oo][jt] = (f32x4){0.f, 0.f, 0.f, 0.f};
        mx[oo][jt] = (f32x4){-INFINITY, -INFINITY, -INFINITY, -INFINITY};
      }

#define T_ISSUE(SET, S) do {                                              \
      int _s = (S);                                                       \
      int _p = _s >> 3; if (_p > 8) _p = 8;                               \
      const _Float16* _a = tg + (_p << 9) + ((_s & 7) << 6);              \
      st[SET][0] = *(const half8*)_a;                                     \
      st[SET][1] = *(const half8*)(_a + 32);                              \
    } while (0)

#define T_WRITE(SET, PAR) do {                                            \
      _Float16* _b = lds + 65536 + (PAR) * 8192;                          \
      *(half8*)&_b[ld] = st[SET][0];                                      \
      *(half8*)&_b[4096 + ld] = st[SET][1];                               \
    } while (0)

    // pipeline prologue: issue K64-steps 0..2; write step 0 to parity 0
    T_ISSUE(0, 0);
    T_ISSUE(1, 1);
    T_ISSUE(2, 2);
    T_WRITE(0, 0);
    asm volatile("s_waitcnt lgkmcnt(0)" ::: "memory");
    __builtin_amdgcn_s_barrier();
    __builtin_amdgcn_sched_barrier(0);

    for (int p = 0; p < 9; ++p) {
#pragma unroll
      for (int kc = 0; kc < 8; ++kc) {          // K64 steps
        int s = p * 8 + kc;
        T_ISSUE((kc + 3) & 3, s + 3);           // issue 3 K64-steps ahead
        T_WRITE((kc + 1) & 3, (kc + 1) & 1);    // stage next step

        const _Float16* buf = lds + 65536 + (kc & 1) * 8192;
#pragma unroll
        for (int kh = 0; kh < 2; ++kh) {
          const _Float16* cur = buf + kh * 4096;
          int kc32 = (kc << 1) + kh;            // 0..15, compile-time
          half8 bfr[2];
#pragma unroll
          for (int jt = 0; jt < 2; jt++) {
            int j = jq * 32 + jt * 16 + lrow;
            bfr[jt] = *(const half8*)&cur[j * 32 + ((lk8 ^ ((j >> 1) & 3)) << 3)];
          }
#pragma unroll
          for (int oo = 0; oo < O; ++oo) {
            half8 afr;
            if (OB + oo == 8) {
              afr = o8f[kc32];
            } else {
              int r = lrow * 8 + OB + oo;
              afr = *(const half8*)&lds[r * 512 + ((((kc32 << 2) + lk8) ^ (r & 7)) << 3)];
            }
            acc[oo][0] = __builtin_amdgcn_mfma_f32_16x16x32_f16(afr, bfr[0], acc[oo][0], 0, 0, 0);
            acc[oo][1] = __builtin_amdgcn_mfma_f32_16x16x32_f16(afr, bfr[1], acc[oo][1], 0, 0, 0);
          }
        }

        if (kc == 7) {                          // end of p: fold max, reset
#pragma unroll
          for (int oo = 0; oo < O; oo++)
#pragma unroll
            for (int jt = 0; jt < 2; jt++) {
#pragma unroll
              for (int e = 0; e < 4; e++)
                mx[oo][jt][e] = fmaxf(mx[oo][jt][e], acc[oo][jt][e]);
              acc[oo][jt] = (f32x4){0.f, 0.f, 0.f, 0.f};
            }
        }
        asm volatile("s_waitcnt lgkmcnt(0)" ::: "memory");
        __builtin_amdgcn_s_barrier();
        __builtin_amdgcn_sched_barrier(0);
      }
    }
#undef T_ISSUE
#undef T_WRITE

    // partial sum over this wave's o-subset
    f32x4 ps[2];
#pragma unroll
    for (int jt = 0; jt < 2; jt++) {
      ps[jt] = mx[0][jt];
#pragma unroll
      for (int oo = 1; oo < O; oo++) ps[jt] += mx[oo][jt];
    }

    // cross-wave o-merge (og1 -> og0) via LDS (T buffers dead), paired by jq
    if (OB != 0) {
#pragma unroll
      for (int jt = 0; jt < 2; jt++)
        *(f32x4*)&ex[((jq * 64 + lane) * 2 + jt) * 4] = ps[jt];
    }
    __syncthreads();
    if (OB == 0) {
      const float* tm = (tsel ? nm : pm) + b * 128;
      int pb = b + tsel * 32;
#pragma unroll
      for (int jt = 0; jt < 2; jt++) {
        ps[jt] += *(const f32x4*)&ex[((jq * 64 + lane) * 2 + jt) * 4];
        int j = jq * 32 + jt * 16 + lrow;
        float tmv = tm[j];
#pragma unroll
        for (int e = 0; e < 4; e++) {
          int i = i0 + (lk8 << 2) + e;
          float m = qmv[i] * tmv;
          simout[((size_t)pb << 14) + (i << 7) + j] = (m > 0.f) ? ps[jt][e] * inv9 : 0.f;
        }
      }
    }
    __syncthreads();   // protect ex / T buffers before next tsel
  }
}

__global__ __launch_bounds__(512, 1) void sim_mfma_kernel(
    const float* __restrict__ A32, const _Float16* __restrict__ Pf,
    const _Float16* __restrict__ Nf,
    const float* __restrict__ qm, const float* __restrict__ pm,
    const float* __restrict__ nm, float* __restrict__ simout)
{
  __shared__ _Float16 lds[81920];       // Q(o0..7) 128KB + T 32KB = 160KiB

  // 256 blocks = 8 xcd * 4 b * 8 ib (pair's i-blocks co-resident per XCD)
  int n = blockIdx.x;
  int xcd = n & 7, slot = n >> 3;
  int b = xcd * 4 + (slot >> 3);
  int ib = slot & 7;
  const float* Q32 = A32 + (size_t)b * BTRD;
  const _Float16* TP = Pf + (size_t)b * BTRD;
  const _Float16* TN = Nf + (size_t)b * BTRD;
  int i0 = ib * 16;

  int tid = threadIdx.x;
  int w = tid >> 6;
  int jq = w & 3;
  if ((w >> 2) == 0)
    sim_run<5, 0>(Q32, TP, TN, lds, i0, tid, jq, b, qm, pm, nm, simout);
  else
    sim_run<4, 5>(Q32, TP, TN, lds, i0, tid, jq, b, qm, pm, nm, simout);
}

// ---------------------------------------------------------------------------
// Stage B1: conv1(3x3, 1->32)+bias+relu+maxpool2. Output NHWC f16.
// ---------------------------------------------------------------------------
__global__ __launch_bounds__(256) void conv1_kernel(
    const float* __restrict__ sim, const float* __restrict__ w1,
    const float* __restrict__ b1, _Float16* __restrict__ x1)
{
  __shared__ float w_s[288];
  __shared__ float b_s[32];
  int tid = threadIdx.x;
  for (int e = tid; e < 288; e += 256) w_s[e] = w1[e];
  if (tid < 32) b_s[tid] = b1[tid];
  __syncthreads();

  int idx = blockIdx.x * 256 + tid;       // 64*64*64
  int x = idx & 63, y = (idx >> 6) & 63, b2 = idx >> 12;
  const float* sb = sim + (size_t)b2 * 16384;

  float patch[4][4];
#pragma unroll
  for (int r = 0; r < 4; r++) {
    int Y = 2 * y - 1 + r;
#pragma unroll
    for (int c = 0; c < 4; c++) {
      int X = 2 * x - 1 + c;
      patch[r][c] = (Y >= 0 && Y < 128 && X >= 0 && X < 128) ? sb[Y * 128 + X] : 0.f;
    }
  }

  _Float16 vout[32];
#pragma unroll
  for (int oc = 0; oc < 32; oc++) {
    float c00 = 0, c01 = 0, c10 = 0, c11 = 0;
#pragma unroll
    for (int tap = 0; tap < 9; tap++) {
      int dy = tap / 3, dx = tap - dy * 3;
      float w = w_s[oc * 9 + tap];
      c00 = fmaf(w, patch[dy][dx], c00);
      c01 = fmaf(w, patch[dy][dx + 1], c01);
      c10 = fmaf(w, patch[dy + 1][dx], c10);
      c11 = fmaf(w, patch[dy + 1][dx + 1], c11);
    }
    float v = fmaxf(fmaxf(c00, c01), fmaxf(c10, c11)) + b_s[oc];
    vout[oc] = (_Float16)fmaxf(v, 0.f);
  }
  _Float16* dst = x1 + (((size_t)b2 * 64 + y) * 64 + x) * 32;
#pragma unroll
  for (int q = 0; q < 4; q++)
    *(half8*)(dst + q * 8) = *(half8*)&vout[q * 8];
}

// ---------------------------------------------------------------------------
// Stage B2 (MFMA): conv2(3x3,32->64)+bias+relu+maxpool2, NHWC f16 in/out.
// ---------------------------------------------------------------------------
__global__ __launch_bounds__(256, 2) void conv2_mfma(
    const _Float16* __restrict__ x1, const _Float16* __restrict__ w2t,
    const float* __restrict__ bb, _Float16* __restrict__ x2)
{
  __shared__ _Float16 in_s[4 * 6 * 66 * 8];     // [k8][rr][px_mem][8]
  __shared__ _Float16 w_s[9 * 64 * 40];         // [tap][oc][ic(+pad)]
  __shared__ _Float16 pool_s[4][32 * 32];       // per wave [px][oc32]

  int b2 = blockIdx.y, ystrip = blockIdx.x;     // 16 strips x 4 conv rows
  int y0 = ystrip * 4;
  int tid = threadIdx.x;
  int w = tid >> 6, lane = tid & 63;
  int wyp = w >> 1, wn = w & 1;
  int lrow = lane & 15, lk8 = lane >> 4;

  {
    int px = tid >> 2, seg = tid & 3;
    const _Float16* base = x1 + ((size_t)b2 * 64) * 64 * 32;
    for (int rr = 0; rr < 6; rr++) {
      int yy = y0 - 1 + rr;
      half8 v = {};
      if (yy >= 0 && yy < 64) v = *(const half8*)(base + ((size_t)yy * 64 + px) * 32 + seg * 8);
      *(half8*)&in_s[((seg * 6 + rr) * 66 + px + 1) * 8] = v;
    }
    if (tid < 48) {
      int pr = tid >> 1, side = tid & 1;
      *(half8*)&in_s[(pr * 66 + side * 65) * 8] = (half8){};
    }
  }
  for (int e = tid; e < 2304; e += 256)
    *(half8*)&w_s[(e >> 2) * 40 + (e & 3) * 8] = *(const half8*)&w2t[e * 8];
  __syncthreads();

  f32x4 acc[2][4][2];
#pragma unroll
  for (int yr = 0; yr < 2; yr++)
#pragma unroll
    for (int xt = 0; xt < 4; xt++)
#pragma unroll
      for (int nt = 0; nt < 2; nt++)
        acc[yr][xt][nt] = (f32x4){0.f, 0.f, 0.f, 0.f};

#pragma unroll
  for (int tap = 0; tap < 9; tap++) {
    int dy = tap / 3, dx = tap - dy * 3;
    half8 bfr[2];
#pragma unroll
    for (int nt = 0; nt < 2; nt++)
      bfr[nt] = *(const half8*)&w_s[(tap * 64 + wn * 32 + nt * 16 + lrow) * 40 + lk8 * 8];
#pragma unroll
    for (int yr = 0; yr < 2; yr++) {
      int rr = 2 * wyp + yr + dy;
#pragma unroll
      for (int xt = 0; xt < 4; xt++) {
        half8 afr = *(const half8*)&in_s[((lk8 * 6 + rr) * 66 + xt * 16 + lrow + dx) * 8];
#pragma unroll
        for (int nt = 0; nt < 2; nt++)
          acc[yr][xt][nt] = __builtin_amdgcn_mfma_f32_16x16x32_f16(afr, bfr[nt], acc[yr][xt][nt], 0, 0, 0);
      }
    }
  }

  float bbv[2] = { bb[wn * 32 + lrow], bb[wn * 32 + 16 + lrow] };
#pragma unroll
  for (int nt = 0; nt < 2; nt++)
#pragma unroll
    for (int xt = 0; xt < 4; xt++)
#pragma unroll
      for (int pe = 0; pe < 2; pe++) {
        float m = fmaxf(fmaxf(acc[0][xt][nt][2 * pe], acc[0][xt][nt][2 * pe + 1]),
                        fmaxf(acc[1][xt][nt][2 * pe], acc[1][xt][nt][2 * pe + 1]));
        float v = fmaxf(m + bbv[nt], 0.f);
        int px = xt * 8 + lk8 * 2 + pe;
        pool_s[w][px * 32 + nt * 16 + lrow] = (_Float16)v;
      }
  __syncthreads();

  {
    int py = ystrip * 2 + wyp;
    int px = lane & 31, half = lane >> 5;
    const _Float16* srcp = &pool_s[w][px * 32 + half * 16];
    _Float16* dst = x2 + (((size_t)b2 * 32 + py) * 32 + px) * 64 + wn * 32 + half * 16;
    *(half8*)dst = *(const half8*)srcp;
    *(half8*)(dst + 8) = *(const half8*)(srcp + 8);
  }
}

// ---------------------------------------------------------------------------
// Stage B3 (MFMA): conv3(3x3,64->128)+bias+relu fused with convf(1x1)+bf.
// ---------------------------------------------------------------------------
__global__ __launch_bounds__(256, 2) void conv3_mfma(
    const _Float16* __restrict__ x2, const _Float16* __restrict__ w3t,
    const float* __restrict__ b3, const float* __restrict__ wf,
    const float* __restrict__ bf, float* __restrict__ shead)
{
  __shared__ _Float16 in_s[8 * 6 * 34 * 8];
  __shared__ _Float16 w_s[9 * 32 * 72];

  int b2 = blockIdx.y, ystrip = blockIdx.x;
  int y0 = ystrip * 4;
  int tid = threadIdx.x, w = tid >> 6, lane = tid & 63;
  int lrow = lane & 15, lk8 = lane >> 4;

  {
    int px = tid >> 3, seg = tid & 7;
    const _Float16* base = x2 + ((size_t)b2 * 32) * 32 * 64;
    for (int rr = 0; rr < 6; rr++) {
      int yy = y0 - 1 + rr;
      half8 v = {};
      if (yy >= 0 && yy < 32) v = *(const half8*)(base + ((size_t)yy * 32 + px) * 64 + seg * 8);
      *(half8*)&in_s[((seg * 6 + rr) * 34 + px + 1) * 8] = v;
    }
    if (tid < 96) {
      int pr = tid >> 1, side = tid & 1;
      *(half8*)&in_s[(pr * 34 + side * 33) * 8] = (half8){};
    }
  }

  f32x4 spart[2];
  spart[0] = (f32x4){0.f, 0.f, 0.f, 0.f};
  spart[1] = (f32x4){0.f, 0.f, 0.f, 0.f};
  int y = y0 + w;

  for (int og = 0; og < 4; og++) {
    __syncthreads();
    for (int e = tid; e < 2304; e += 256) {
      int s = e & 7, o = (e >> 3) & 31, tap = e >> 8;
      *(half8*)&w_s[(tap * 32 + o) * 72 + s * 8] =
          *(const half8*)&w3t[((size_t)(tap * 128 + og * 32 + o)) * 64 + s * 8];
    }
    __syncthreads();

    f32x4 acc[2][2];
#pragma unroll
    for (int mt = 0; mt < 2; mt++)
#pragma unroll
      for (int nt = 0; nt < 2; nt++)
        acc[mt][nt] = (f32x4){0.f, 0.f, 0.f, 0.f};

#pragma unroll
    for (int tap = 0; tap < 9; tap++) {
      int dy = tap / 3, dx = tap - dy * 3;
#pragma unroll
      for (int kc = 0; kc < 2; kc++) {
        half8 bfr[2];
#pragma unroll
        for (int nt = 0; nt < 2; nt++)
          bfr[nt] = *(const half8*)&w_s[(tap * 32 + nt * 16 + lrow) * 72 + kc * 32 + lk8 * 8];
#pragma unroll
        for (int mt = 0; mt < 2; mt++) {
          half8 afr = *(const half8*)&in_s[(((kc * 4 + lk8) * 6 + w + dy) * 34 + mt * 16 + lrow + dx) * 8];
#pragma unroll
          for (int nt = 0; nt < 2; nt++)
            acc[mt][nt] = __builtin_amdgcn_mfma_f32_16x16x32_f16(afr, bfr[nt], acc[mt][nt], 0, 0, 0);
        }
      }
    }

#pragma unroll
    for (int nt = 0; nt < 2; nt++) {
      int oc = og * 32 + nt * 16 + lrow;
      float b3v = b3[oc], wfv = wf[oc];
#pragma unroll
      for (int mt = 0; mt < 2; mt++)
#pragma unroll
        for (int e = 0; e < 4; e++)
          spart[mt][e] = fmaf(fmaxf(acc[mt][nt][e] + b3v, 0.f), wfv, spart[mt][e]);
    }
  }

#pragma unroll
  for (int mt = 0; mt < 2; mt++)
#pragma unroll
    for (int e = 0; e < 4; e++) {
      float v = spart[mt][e];
      v += __shfl_xor(v, 1); v += __shfl_xor(v, 2);
      v += __shfl_xor(v, 4); v += __shfl_xor(v, 8);
      spart[mt][e] = v;
    }
  if (lrow == 0) {
    float bfv = bf[0];
#pragma unroll
    for (int mt = 0; mt < 2; mt++)
#pragma unroll
      for (int e = 0; e < 4; e++) {
        int x = mt * 16 + lk8 * 4 + e;
        shead[(size_t)b2 * 1024 + y * 32 + x] = spart[mt][e] + bfv;
      }
  }
}

// ---------------------------------------------------------------------------
// Stage C: loss partials + clip + chamfer per b2.
// ---------------------------------------------------------------------------
__global__ __launch_bounds__(256) void head_final_kernel(
    const float* __restrict__ shead, const float* __restrict__ qm,
    const float* __restrict__ pm, const float* __restrict__ nm,
    float* __restrict__ out, float* __restrict__ loss_ws)
{
  int b2 = blockIdx.x, b = b2 & 31, g = b2 >> 5;
  const float* qmv = qm + b * 128;
  const float* tmv = (g ? nm : pm) + b * 128;

  __shared__ float mq4[32], mt4[32];
  __shared__ float red[256];
  __shared__ float rowv[32], rowm[32];

  int tid = threadIdx.x;
  if (tid < 32) {
    float a = qmv[tid * 4];
    a = fmaxf(a, qmv[tid * 4 + 1]); a = fmaxf(a, qmv[tid * 4 + 2]); a = fmaxf(a, qmv[tid * 4 + 3]);
    mq4[tid] = a;
    float c = tmv[tid * 4];
    c = fmaxf(c, tmv[tid * 4 + 1]); c = fmaxf(c, tmv[tid * 4 + 2]); c = fmaxf(c, tmv[tid * 4 + 3]);
    mt4[tid] = c;
  }
  __syncthreads();

  const float* s = shead + (size_t)b2 * 1024;
  float lp = 0.f;
#pragma unroll
  for (int r = 0; r < 4; r++) {
    float v = s[tid + 256 * r];
    lp += fmaxf(-1.f - v, 0.f) + fmaxf(v - 1.f, 0.f);
  }
  red[tid] = lp;
  __syncthreads();
  for (int off = 128; off; off >>= 1) {
    if (tid < off) red[tid] += red[tid + off];
    __syncthreads();
  }
  if (tid == 0) loss_ws[b2] = red[0];

  if (tid < 32) {
    int y = tid;
    float mqy = mq4[y];
    float rmax = -INFINITY, mm = 0.f;
    for (int x = 0; x < 32; x++) {
      float m = mqy * mt4[x];
      mm = fmaxf(mm, m);
      float v = s[y * 32 + x];
      v = fminf(fmaxf(v, -1.f), 1.f);
      rmax = fmaxf(rmax, m > 0.f ? v : -INFINITY);
    }
    rowv[y] = (mm > 0.f) ? rmax : 0.f;
    rowm[y] = mm;
  }
  __syncthreads();
  if (tid == 0) {
    float ss = 0.f, sm = 0.f;
    for (int y = 0; y < 32; y++) { ss += rowv[y]; sm += rowm[y]; }
    out[b2] = ss / sm;
  }
}

__global__ void loss_sum_kernel(const float* __restrict__ loss_ws, float* __restrict__ out)
{
  float v = loss_ws[threadIdx.x];
#pragma unroll
  for (int off = 32; off >= 1; off >>= 1) v += __shfl_down(v, off);
  if (threadIdx.x == 0) out[64] = v;
}

// ---------------------------------------------------------------------------
extern "C" void kernel_launch(void* const* d_in, const int* in_sizes, int n_in,
                              void* d_out, int out_size, void* d_ws, size_t ws_size,
                              hipStream_t stream)
{
  (void)in_sizes; (void)n_in; (void)out_size; (void)ws_size;
  const float* A   = (const float*)d_in[0];
  const float* P   = (const float*)d_in[1];
  const float* Nn  = (const float*)d_in[2];
  const float* qm  = (const float*)d_in[3];
  const float* pm  = (const float*)d_in[4];
  const float* nm  = (const float*)d_in[5];
  const float* w1  = (const float*)d_in[6];
  const float* b1  = (const float*)d_in[7];
  const float* w2  = (const float*)d_in[8];
  const float* b2w = (const float*)d_in[9];
  const float* w3  = (const float*)d_in[10];
  const float* b3  = (const float*)d_in[11];
  const float* wf  = (const float*)d_in[12];
  const float* bf  = (const float*)d_in[13];
  float* out = (float*)d_out;

  const size_t F16SZ = (size_t)BTRD * 32 * sizeof(_Float16);  // 37,748,736 B
  char* ws = (char*)d_ws;
  _Float16* Pf = (_Float16*)(ws);
  _Float16* Nf = (_Float16*)(ws + F16SZ);
  char* ws2 = ws + 2 * F16SZ;
  float*     sim   = (float*)(ws2);                               // 4 MB
  _Float16*  x1    = (_Float16*)(ws2 + (4u << 20));               // 16 MB NHWC
  _Float16*  x2    = (_Float16*)(ws2 + (20u << 20));              // 8 MB NHWC
  float*     shead = (float*)(ws2 + (28u << 20));                 // 256 KB
  _Float16*  w2t   = (_Float16*)(ws2 + (29u << 20));              // 36 KB
  _Float16*  w3t   = (_Float16*)(ws2 + (29u << 20) + (256u << 10)); // 144 KB
  float*     lws   = (float*)(ws2 + (30u << 20));

  prep_kernel<<<18792, 256, 0, stream>>>(P, Nn, Pf, Nf, w2, w3, w2t, w3t);

  sim_mfma_kernel<<<256, 512, 0, stream>>>(A, Pf, Nf, qm, pm, nm, sim);
  conv1_kernel<<<1024, 256, 0, stream>>>(sim, w1, b1, x1);
  conv2_mfma<<<dim3(16, 64), 256, 0, stream>>>(x1, w2t, b2w, x2);
  conv3_mfma<<<dim3(8, 64), 256, 0, stream>>>(x2, w3t, b3, wf, bf, shead);
  head_final_kernel<<<64, 256, 0, stream>>>(shead, qm, pm, nm, out, lws);
  loss_sum_kernel<<<1, 64, 0, stream>>>(lws, out);
}

// Round 15
// 188.823 us; speedup vs baseline: 1.4488x; 1.4488x over previous
//
#include <hip/hip_runtime.h>
#include <math.h>

// Problem constants: B=32, T=128, R=9, D=512. 64 pairs (32 pos + 32 neg).
#define BTRD (128*9*512)

typedef _Float16 half8 __attribute__((ext_vector_type(8)));
typedef float f32x4 __attribute__((ext_vector_type(4)));

// ---------------------------------------------------------------------------
// prep: fp32->f16 cvt for P/N (A is consumed as f32 by sim) + weight transforms
// ---------------------------------------------------------------------------
__global__ __launch_bounds__(256) void prep_kernel(
    const float* __restrict__ P, const float* __restrict__ Nn,
    _Float16* __restrict__ Pf, _Float16* __restrict__ Nf,
    const float* __restrict__ w2, const float* __restrict__ w3,
    _Float16* __restrict__ w2t, _Float16* __restrict__ w3t)
{
  int bid = blockIdx.x;
  if (bid < 18432) {
    int which = bid / 9216;
    const float* in = which == 0 ? P : Nn;
    _Float16* out = which == 0 ? Pf : Nf;
    int idx = (bid - which * 9216) * 256 + threadIdx.x;
    const float4* in4 = (const float4*)in;
    float4 a = in4[idx * 2], c = in4[idx * 2 + 1];
    half8 h = { (_Float16)a.x, (_Float16)a.y, (_Float16)a.z, (_Float16)a.w,
                (_Float16)c.x, (_Float16)c.y, (_Float16)c.z, (_Float16)c.w };
    ((half8*)out)[idx] = h;
  } else {
    int idx = (bid - 18432) * 256 + threadIdx.x;
    if (idx < 18432) {
      int tap = idx >> 11, oc = (idx >> 5) & 63, ic = idx & 31;
      w2t[idx] = (_Float16)w2[(oc * 32 + ic) * 9 + tap];
    } else if (idx < 18432 + 73728) {
      int j = idx - 18432;
      int tap = j >> 13, oc = (j >> 6) & 127, ic = j & 63;
      w3t[j] = (_Float16)w3[(oc * 64 + ic) * 9 + tap];
    }
  }
}

// ---------------------------------------------------------------------------
// Stage A (MFMA v12): v11 with the Q-swizzle FIXED.
// v11's bug: Q rows r = i*8+o made swz = r&7 = o CONSTANT across the 16
// fragment lanes -> no swizzle -> 16-way bank conflict (6.6e7 counter).
// Fix: swz(r) = (r>>3)&7 = i-index, which varies per lane (lrow) exactly
// like v7's verified pattern. Applied on BOTH prologue write and read.
// Structure (unchanged from v11): Q o0..7 in LDS 128KB; o=8 A-frags in 32
// VGPRs (og1 lanes); T 2 parity x 2 kh sub-buffers (v7 layout); K64 steps,
// ONE lgkmcnt(0)+s_barrier per step (half of v7's barrier count).
// 512 thr = 8 waves = 2/SIMD. Wave = (og: o 0..4 / 5..8) x (jq: 32 j).
// Both tsel per block; 256 blocks = 1/CU, XCD-chunked remap.
// ---------------------------------------------------------------------------
template<int O, int OB>
__device__ __forceinline__ void sim_run(
    const float* __restrict__ Q32, const _Float16* __restrict__ TP,
    const _Float16* __restrict__ TN,
    _Float16* __restrict__ lds, int i0, int tid, int jq, int b,
    const float* __restrict__ qm, const float* __restrict__ pm,
    const float* __restrict__ nm, float* __restrict__ simout)
{
  int lane = tid & 63;
  int lrow = lane & 15, lk8 = lane >> 4;

  const float* qb = Q32 + ((size_t)(i0 * 9) << 9);

  // ---- Q prologue: o 0..7 rows -> swizzled LDS (8192 chunks / 512 thr) ----
  // swz(r) = (r>>3)&7 (the i-index) -- varies across fragment lanes.
#pragma unroll
  for (int it = 0; it < 16; it++) {
    int c = it * 512 + tid;
    int r = c >> 6, sp = c & 63;              // r = i*8 + o (o in 0..7)
    const float* src = qb + ((size_t)((r >> 3) * 9 + (r & 7)) << 9) + (sp << 3);
    float4 a = *(const float4*)src;
    float4 cc = *(const float4*)(src + 4);
    half8 h = { (_Float16)a.x, (_Float16)a.y, (_Float16)a.z, (_Float16)a.w,
                (_Float16)cc.x, (_Float16)cc.y, (_Float16)cc.z, (_Float16)cc.w };
    *(half8*)&lds[r * 512 + ((sp ^ ((r >> 3) & 7)) << 3)] = h;
  }

  // ---- o=8 register cache (og1 lanes only): 16 x half8 = 32 VGPR ----
  half8 o8f[16];
  if (OB != 0) {
    const float* o8src = qb + ((size_t)(lrow * 9 + 8) << 9) + (lk8 << 3);
#pragma unroll
    for (int c = 0; c < 16; c++) {
      float4 a = *(const float4*)(o8src + (c << 5));
      float4 cc = *(const float4*)(o8src + (c << 5) + 4);
      o8f[c] = (half8){ (_Float16)a.x, (_Float16)a.y, (_Float16)a.z, (_Float16)a.w,
                        (_Float16)cc.x, (_Float16)cc.y, (_Float16)cc.z, (_Float16)cc.w };
    }
  }
  __syncthreads();

  // per-thread T chunk: row jc = tid>>2, slot spc = tid&3 (within each 8KB
  // kh sub-buffer of 128 rows x 32 f16). Same mapping/swizzle as v7.
  int jc = tid >> 2, spc = tid & 3;
  int ld = jc * 32 + ((spc ^ ((jc >> 1) & 3)) << 3);

  float* ex = (float*)(lds + 65536);
  const float* qmv = qm + b * 128;
  const float inv9 = 1.0f / 9.0f;

  for (int tsel = 0; tsel < 2; ++tsel) {
    const _Float16* tg = (tsel ? TN : TP) + (size_t)jc * 4608 + (spc << 3);

    half8 st[4][2];       // rotating sets x 2 kh chunks, static indices only
    f32x4 acc[O][2], mx[O][2];
#pragma unroll
    for (int oo = 0; oo < O; oo++)
#pragma unroll
      for (int jt = 0; jt < 2; jt++) {
        acc[oo][jt] = (f32x4){0.f, 0.f, 0.f, 0.f};
        mx[oo][jt] = (f32x4){-INFINITY, -INFINITY, -INFINITY, -INFINITY};
      }

#define T_ISSUE(SET, S) do {                                              \
      int _s = (S);                                                       \
      int _p = _s >> 3; if (_p > 8) _p = 8;                               \
      const _Float16* _a = tg + (_p << 9) + ((_s & 7) << 6);              \
      st[SET][0] = *(const half8*)_a;                                     \
      st[SET][1] = *(const half8*)(_a + 32);                              \
    } while (0)

#define T_WRITE(SET, PAR) do {                                            \
      _Float16* _b = lds + 65536 + (PAR) * 8192;                          \
      *(half8*)&_b[ld] = st[SET][0];                                      \
      *(half8*)&_b[4096 + ld] = st[SET][1];                               \
    } while (0)

    // pipeline prologue: issue K64-steps 0..2; write step 0 to parity 0
    T_ISSUE(0, 0);
    T_ISSUE(1, 1);
    T_ISSUE(2, 2);
    T_WRITE(0, 0);
    asm volatile("s_waitcnt lgkmcnt(0)" ::: "memory");
    __builtin_amdgcn_s_barrier();
    __builtin_amdgcn_sched_barrier(0);

    for (int p = 0; p < 9; ++p) {
#pragma unroll
      for (int kc = 0; kc < 8; ++kc) {          // K64 steps
        int s = p * 8 + kc;
        T_ISSUE((kc + 3) & 3, s + 3);           // issue 3 K64-steps ahead
        T_WRITE((kc + 1) & 3, (kc + 1) & 1);    // stage next step

        const _Float16* buf = lds + 65536 + (kc & 1) * 8192;
#pragma unroll
        for (int kh = 0; kh < 2; ++kh) {
          const _Float16* cur = buf + kh * 4096;
          int kc32 = (kc << 1) + kh;            // 0..15, compile-time
          half8 bfr[2];
#pragma unroll
          for (int jt = 0; jt < 2; jt++) {
            int j = jq * 32 + jt * 16 + lrow;
            bfr[jt] = *(const half8*)&cur[j * 32 + ((lk8 ^ ((j >> 1) & 3)) << 3)];
          }
#pragma unroll
          for (int oo = 0; oo < O; ++oo) {
            half8 afr;
            if (OB + oo == 8) {
              afr = o8f[kc32];
            } else {
              int r = lrow * 8 + OB + oo;       // r>>3 = lrow (OB+oo <= 7)
              afr = *(const half8*)&lds[r * 512 + ((((kc32 << 2) + lk8) ^ (lrow & 7)) << 3)];
            }
            acc[oo][0] = __builtin_amdgcn_mfma_f32_16x16x32_f16(afr, bfr[0], acc[oo][0], 0, 0, 0);
            acc[oo][1] = __builtin_amdgcn_mfma_f32_16x16x32_f16(afr, bfr[1], acc[oo][1], 0, 0, 0);
          }
        }

        if (kc == 7) {                          // end of p: fold max, reset
#pragma unroll
          for (int oo = 0; oo < O; oo++)
#pragma unroll
            for (int jt = 0; jt < 2; jt++) {
#pragma unroll
              for (int e = 0; e < 4; e++)
                mx[oo][jt][e] = fmaxf(mx[oo][jt][e], acc[oo][jt][e]);
              acc[oo][jt] = (f32x4){0.f, 0.f, 0.f, 0.f};
            }
        }
        asm volatile("s_waitcnt lgkmcnt(0)" ::: "memory");
        __builtin_amdgcn_s_barrier();
        __builtin_amdgcn_sched_barrier(0);
      }
    }
#undef T_ISSUE
#undef T_WRITE

    // partial sum over this wave's o-subset
    f32x4 ps[2];
#pragma unroll
    for (int jt = 0; jt < 2; jt++) {
      ps[jt] = mx[0][jt];
#pragma unroll
      for (int oo = 1; oo < O; oo++) ps[jt] += mx[oo][jt];
    }

    // cross-wave o-merge (og1 -> og0) via LDS (T buffers dead), paired by jq
    if (OB != 0) {
#pragma unroll
      for (int jt = 0; jt < 2; jt++)
        *(f32x4*)&ex[((jq * 64 + lane) * 2 + jt) * 4] = ps[jt];
    }
    __syncthreads();
    if (OB == 0) {
      const float* tm = (tsel ? nm : pm) + b * 128;
      int pb = b + tsel * 32;
#pragma unroll
      for (int jt = 0; jt < 2; jt++) {
        ps[jt] += *(const f32x4*)&ex[((jq * 64 + lane) * 2 + jt) * 4];
        int j = jq * 32 + jt * 16 + lrow;
        float tmv = tm[j];
#pragma unroll
        for (int e = 0; e < 4; e++) {
          int i = i0 + (lk8 << 2) + e;
          float m = qmv[i] * tmv;
          simout[((size_t)pb << 14) + (i << 7) + j] = (m > 0.f) ? ps[jt][e] * inv9 : 0.f;
        }
      }
    }
    __syncthreads();   // protect ex / T buffers before next tsel
  }
}

__global__ __launch_bounds__(512, 1) void sim_mfma_kernel(
    const float* __restrict__ A32, const _Float16* __restrict__ Pf,
    const _Float16* __restrict__ Nf,
    const float* __restrict__ qm, const float* __restrict__ pm,
    const float* __restrict__ nm, float* __restrict__ simout)
{
  __shared__ _Float16 lds[81920];       // Q(o0..7) 128KB + T 32KB = 160KiB

  // 256 blocks = 8 xcd * 4 b * 8 ib (pair's i-blocks co-resident per XCD)
  int n = blockIdx.x;
  int xcd = n & 7, slot = n >> 3;
  int b = xcd * 4 + (slot >> 3);
  int ib = slot & 7;
  const float* Q32 = A32 + (size_t)b * BTRD;
  const _Float16* TP = Pf + (size_t)b * BTRD;
  const _Float16* TN = Nf + (size_t)b * BTRD;
  int i0 = ib * 16;

  int tid = threadIdx.x;
  int w = tid >> 6;
  int jq = w & 3;
  if ((w >> 2) == 0)
    sim_run<5, 0>(Q32, TP, TN, lds, i0, tid, jq, b, qm, pm, nm, simout);
  else
    sim_run<4, 5>(Q32, TP, TN, lds, i0, tid, jq, b, qm, pm, nm, simout);
}

// ---------------------------------------------------------------------------
// Stage B1: conv1(3x3, 1->32)+bias+relu+maxpool2. Output NHWC f16.
// ---------------------------------------------------------------------------
__global__ __launch_bounds__(256) void conv1_kernel(
    const float* __restrict__ sim, const float* __restrict__ w1,
    const float* __restrict__ b1, _Float16* __restrict__ x1)
{
  __shared__ float w_s[288];
  __shared__ float b_s[32];
  int tid = threadIdx.x;
  for (int e = tid; e < 288; e += 256) w_s[e] = w1[e];
  if (tid < 32) b_s[tid] = b1[tid];
  __syncthreads();

  int idx = blockIdx.x * 256 + tid;       // 64*64*64
  int x = idx & 63, y = (idx >> 6) & 63, b2 = idx >> 12;
  const float* sb = sim + (size_t)b2 * 16384;

  float patch[4][4];
#pragma unroll
  for (int r = 0; r < 4; r++) {
    int Y = 2 * y - 1 + r;
#pragma unroll
    for (int c = 0; c < 4; c++) {
      int X = 2 * x - 1 + c;
      patch[r][c] = (Y >= 0 && Y < 128 && X >= 0 && X < 128) ? sb[Y * 128 + X] : 0.f;
    }
  }

  _Float16 vout[32];
#pragma unroll
  for (int oc = 0; oc < 32; oc++) {
    float c00 = 0, c01 = 0, c10 = 0, c11 = 0;
#pragma unroll
    for (int tap = 0; tap < 9; tap++) {
      int dy = tap / 3, dx = tap - dy * 3;
      float w = w_s[oc * 9 + tap];
      c00 = fmaf(w, patch[dy][dx], c00);
      c01 = fmaf(w, patch[dy][dx + 1], c01);
      c10 = fmaf(w, patch[dy + 1][dx], c10);
      c11 = fmaf(w, patch[dy + 1][dx + 1], c11);
    }
    float v = fmaxf(fmaxf(c00, c01), fmaxf(c10, c11)) + b_s[oc];
    vout[oc] = (_Float16)fmaxf(v, 0.f);
  }
  _Float16* dst = x1 + (((size_t)b2 * 64 + y) * 64 + x) * 32;
#pragma unroll
  for (int q = 0; q < 4; q++)
    *(half8*)(dst + q * 8) = *(half8*)&vout[q * 8];
}

// ---------------------------------------------------------------------------
// Stage B2 (MFMA): conv2(3x3,32->64)+bias+relu+maxpool2, NHWC f16 in/out.
// ---------------------------------------------------------------------------
__global__ __launch_bounds__(256, 2) void conv2_mfma(
    const _Float16* __restrict__ x1, const _Float16* __restrict__ w2t,
    const float* __restrict__ bb, _Float16* __restrict__ x2)
{
  __shared__ _Float16 in_s[4 * 6 * 66 * 8];     // [k8][rr][px_mem][8]
  __shared__ _Float16 w_s[9 * 64 * 40];         // [tap][oc][ic(+pad)]
  __shared__ _Float16 pool_s[4][32 * 32];       // per wave [px][oc32]

  int b2 = blockIdx.y, ystrip = blockIdx.x;     // 16 strips x 4 conv rows
  int y0 = ystrip * 4;
  int tid = threadIdx.x;
  int w = tid >> 6, lane = tid & 63;
  int wyp = w >> 1, wn = w & 1;
  int lrow = lane & 15, lk8 = lane >> 4;

  {
    int px = tid >> 2, seg = tid & 3;
    const _Float16* base = x1 + ((size_t)b2 * 64) * 64 * 32;
    for (int rr = 0; rr < 6; rr++) {
      int yy = y0 - 1 + rr;
      half8 v = {};
      if (yy >= 0 && yy < 64) v = *(const half8*)(base + ((size_t)yy * 64 + px) * 32 + seg * 8);
      *(half8*)&in_s[((seg * 6 + rr) * 66 + px + 1) * 8] = v;
    }
    if (tid < 48) {
      int pr = tid >> 1, side = tid & 1;
      *(half8*)&in_s[(pr * 66 + side * 65) * 8] = (half8){};
    }
  }
  for (int e = tid; e < 2304; e += 256)
    *(half8*)&w_s[(e >> 2) * 40 + (e & 3) * 8] = *(const half8*)&w2t[e * 8];
  __syncthreads();

  f32x4 acc[2][4][2];
#pragma unroll
  for (int yr = 0; yr < 2; yr++)
#pragma unroll
    for (int xt = 0; xt < 4; xt++)
#pragma unroll
      for (int nt = 0; nt < 2; nt++)
        acc[yr][xt][nt] = (f32x4){0.f, 0.f, 0.f, 0.f};

#pragma unroll
  for (int tap = 0; tap < 9; tap++) {
    int dy = tap / 3, dx = tap - dy * 3;
    half8 bfr[2];
#pragma unroll
    for (int nt = 0; nt < 2; nt++)
      bfr[nt] = *(const half8*)&w_s[(tap * 64 + wn * 32 + nt * 16 + lrow) * 40 + lk8 * 8];
#pragma unroll
    for (int yr = 0; yr < 2; yr++) {
      int rr = 2 * wyp + yr + dy;
#pragma unroll
      for (int xt = 0; xt < 4; xt++) {
        half8 afr = *(const half8*)&in_s[((lk8 * 6 + rr) * 66 + xt * 16 + lrow + dx) * 8];
#pragma unroll
        for (int nt = 0; nt < 2; nt++)
          acc[yr][xt][nt] = __builtin_amdgcn_mfma_f32_16x16x32_f16(afr, bfr[nt], acc[yr][xt][nt], 0, 0, 0);
      }
    }
  }

  float bbv[2] = { bb[wn * 32 + lrow], bb[wn * 32 + 16 + lrow] };
#pragma unroll
  for (int nt = 0; nt < 2; nt++)
#pragma unroll
    for (int xt = 0; xt < 4; xt++)
#pragma unroll
      for (int pe = 0; pe < 2; pe++) {
        float m = fmaxf(fmaxf(acc[0][xt][nt][2 * pe], acc[0][xt][nt][2 * pe + 1]),
                        fmaxf(acc[1][xt][nt][2 * pe], acc[1][xt][nt][2 * pe + 1]));
        float v = fmaxf(m + bbv[nt], 0.f);
        int px = xt * 8 + lk8 * 2 + pe;
        pool_s[w][px * 32 + nt * 16 + lrow] = (_Float16)v;
      }
  __syncthreads();

  {
    int py = ystrip * 2 + wyp;
    int px = lane & 31, half = lane >> 5;
    const _Float16* srcp = &pool_s[w][px * 32 + half * 16];
    _Float16* dst = x2 + (((size_t)b2 * 32 + py) * 32 + px) * 64 + wn * 32 + half * 16;
    *(half8*)dst = *(const half8*)srcp;
    *(half8*)(dst + 8) = *(const half8*)(srcp + 8);
  }
}

// ---------------------------------------------------------------------------
// Stage B3 (MFMA): conv3(3x3,64->128)+bias+relu fused with convf(1x1)+bf.
// ---------------------------------------------------------------------------
__global__ __launch_bounds__(256, 2) void conv3_mfma(
    const _Float16* __restrict__ x2, const _Float16* __restrict__ w3t,
    const float* __restrict__ b3, const float* __restrict__ wf,
    const float* __restrict__ bf, float* __restrict__ shead)
{
  __shared__ _Float16 in_s[8 * 6 * 34 * 8];
  __shared__ _Float16 w_s[9 * 32 * 72];

  int b2 = blockIdx.y, ystrip = blockIdx.x;
  int y0 = ystrip * 4;
  int tid = threadIdx.x, w = tid >> 6, lane = tid & 63;
  int lrow = lane & 15, lk8 = lane >> 4;

  {
    int px = tid >> 3, seg = tid & 7;
    const _Float16* base = x2 + ((size_t)b2 * 32) * 32 * 64;
    for (int rr = 0; rr < 6; rr++) {
      int yy = y0 - 1 + rr;
      half8 v = {};
      if (yy >= 0 && yy < 32) v = *(const half8*)(base + ((size_t)yy * 32 + px) * 64 + seg * 8);
      *(half8*)&in_s[((seg * 6 + rr) * 34 + px + 1) * 8] = v;
    }
    if (tid < 96) {
      int pr = tid >> 1, side = tid & 1;
      *(half8*)&in_s[(pr * 34 + side * 33) * 8] = (half8){};
    }
  }

  f32x4 spart[2];
  spart[0] = (f32x4){0.f, 0.f, 0.f, 0.f};
  spart[1] = (f32x4){0.f, 0.f, 0.f, 0.f};
  int y = y0 + w;

  for (int og = 0; og < 4; og++) {
    __syncthreads();
    for (int e = tid; e < 2304; e += 256) {
      int s = e & 7, o = (e >> 3) & 31, tap = e >> 8;
      *(half8*)&w_s[(tap * 32 + o) * 72 + s * 8] =
          *(const half8*)&w3t[((size_t)(tap * 128 + og * 32 + o)) * 64 + s * 8];
    }
    __syncthreads();

    f32x4 acc[2][2];
#pragma unroll
    for (int mt = 0; mt < 2; mt++)
#pragma unroll
      for (int nt = 0; nt < 2; nt++)
        acc[mt][nt] = (f32x4){0.f, 0.f, 0.f, 0.f};

#pragma unroll
    for (int tap = 0; tap < 9; tap++) {
      int dy = tap / 3, dx = tap - dy * 3;
#pragma unroll
      for (int kc = 0; kc < 2; kc++) {
        half8 bfr[2];
#pragma unroll
        for (int nt = 0; nt < 2; nt++)
          bfr[nt] = *(const half8*)&w_s[(tap * 32 + nt * 16 + lrow) * 72 + kc * 32 + lk8 * 8];
#pragma unroll
        for (int mt = 0; mt < 2; mt++) {
          half8 afr = *(const half8*)&in_s[(((kc * 4 + lk8) * 6 + w + dy) * 34 + mt * 16 + lrow + dx) * 8];
#pragma unroll
          for (int nt = 0; nt < 2; nt++)
            acc[mt][nt] = __builtin_amdgcn_mfma_f32_16x16x32_f16(afr, bfr[nt], acc[mt][nt], 0, 0, 0);
        }
      }
    }

#pragma unroll
    for (int nt = 0; nt < 2; nt++) {
      int oc = og * 32 + nt * 16 + lrow;
      float b3v = b3[oc], wfv = wf[oc];
#pragma unroll
      for (int mt = 0; mt < 2; mt++)
#pragma unroll
        for (int e = 0; e < 4; e++)
          spart[mt][e] = fmaf(fmaxf(acc[mt][nt][e] + b3v, 0.f), wfv, spart[mt][e]);
    }
  }

#pragma unroll
  for (int mt = 0; mt < 2; mt++)
#pragma unroll
    for (int e = 0; e < 4; e++) {
      float v = spart[mt][e];
      v += __shfl_xor(v, 1); v += __shfl_xor(v, 2);
      v += __shfl_xor(v, 4); v += __shfl_xor(v, 8);
      spart[mt][e] = v;
    }
  if (lrow == 0) {
    float bfv = bf[0];
#pragma unroll
    for (int mt = 0; mt < 2; mt++)
#pragma unroll
      for (int e = 0; e < 4; e++) {
        int x = mt * 16 + lk8 * 4 + e;
        shead[(size_t)b2 * 1024 + y * 32 + x] = spart[mt][e] + bfv;
      }
  }
}

// ---------------------------------------------------------------------------
// Stage C: loss partials + clip + chamfer per b2.
// ---------------------------------------------------------------------------
__global__ __launch_bounds__(256) void head_final_kernel(
    const float* __restrict__ shead, const float* __restrict__ qm,
    const float* __restrict__ pm, const float* __restrict__ nm,
    float* __restrict__ out, float* __restrict__ loss_ws)
{
  int b2 = blockIdx.x, b = b2 & 31, g = b2 >> 5;
  const float* qmv = qm + b * 128;
  const float* tmv = (g ? nm : pm) + b * 128;

  __shared__ float mq4[32], mt4[32];
  __shared__ float red[256];
  __shared__ float rowv[32], rowm[32];

  int tid = threadIdx.x;
  if (tid < 32) {
    float a = qmv[tid * 4];
    a = fmaxf(a, qmv[tid * 4 + 1]); a = fmaxf(a, qmv[tid * 4 + 2]); a = fmaxf(a, qmv[tid * 4 + 3]);
    mq4[tid] = a;
    float c = tmv[tid * 4];
    c = fmaxf(c, tmv[tid * 4 + 1]); c = fmaxf(c, tmv[tid * 4 + 2]); c = fmaxf(c, tmv[tid * 4 + 3]);
    mt4[tid] = c;
  }
  __syncthreads();

  const float* s = shead + (size_t)b2 * 1024;
  float lp = 0.f;
#pragma unroll
  for (int r = 0; r < 4; r++) {
    float v = s[tid + 256 * r];
    lp += fmaxf(-1.f - v, 0.f) + fmaxf(v - 1.f, 0.f);
  }
  red[tid] = lp;
  __syncthreads();
  for (int off = 128; off; off >>= 1) {
    if (tid < off) red[tid] += red[tid + off];
    __syncthreads();
  }
  if (tid == 0) loss_ws[b2] = red[0];

  if (tid < 32) {
    int y = tid;
    float mqy = mq4[y];
    float rmax = -INFINITY, mm = 0.f;
    for (int x = 0; x < 32; x++) {
      float m = mqy * mt4[x];
      mm = fmaxf(mm, m);
      float v = s[y * 32 + x];
      v = fminf(fmaxf(v, -1.f), 1.f);
      rmax = fmaxf(rmax, m > 0.f ? v : -INFINITY);
    }
    rowv[y] = (mm > 0.f) ? rmax : 0.f;
    rowm[y] = mm;
  }
  __syncthreads();
  if (tid == 0) {
    float ss = 0.f, sm = 0.f;
    for (int y = 0; y < 32; y++) { ss += rowv[y]; sm += rowm[y]; }
    out[b2] = ss / sm;
  }
}

__global__ void loss_sum_kernel(const float* __restrict__ loss_ws, float* __restrict__ out)
{
  float v = loss_ws[threadIdx.x];
#pragma unroll
  for (int off = 32; off >= 1; off >>= 1) v += __shfl_down(v, off);
  if (threadIdx.x == 0) out[64] = v;
}

// ---------------------------------------------------------------------------
extern "C" void kernel_launch(void* const* d_in, const int* in_sizes, int n_in,
                              void* d_out, int out_size, void* d_ws, size_t ws_size,
                              hipStream_t stream)
{
  (void)in_sizes; (void)n_in; (void)out_size; (void)ws_size;
  const float* A   = (const float*)d_in[0];
  const float* P   = (const float*)d_in[1];
  const float* Nn  = (const float*)d_in[2];
  const float* qm  = (const float*)d_in[3];
  const float* pm  = (const float*)d_in[4];
  const float* nm  = (const float*)d_in[5];
  const float* w1  = (const float*)d_in[6];
  const float* b1  = (const float*)d_in[7];
  const float* w2  = (const float*)d_in[8];
  const float* b2w = (const float*)d_in[9];
  const float* w3  = (const float*)d_in[10];
  const float* b3  = (const float*)d_in[11];
  const float* wf  = (const float*)d_in[12];
  const float* bf  = (const float*)d_in[13];
  float* out = (float*)d_out;

  const size_t F16SZ = (size_t)BTRD * 32 * sizeof(_Float16);  // 37,748,736 B
  char* ws = (char*)d_ws;
  _Float16* Pf = (_Float16*)(ws);
  _Float16* Nf = (_Float16*)(ws + F16SZ);
  char* ws2 = ws + 2 * F16SZ;
  float*     sim   = (float*)(ws2);                               // 4 MB
  _Float16*  x1    = (_Float16*)(ws2 + (4u << 20));               // 16 MB NHWC
  _Float16*  x2    = (_Float16*)(ws2 + (20u << 20));              // 8 MB NHWC
  float*     shead = (float*)(ws2 + (28u << 20));                 // 256 KB
  _Float16*  w2t   = (_Float16*)(ws2 + (29u << 20));              // 36 KB
  _Float16*  w3t   = (_Float16*)(ws2 + (29u << 20) + (256u << 10)); // 144 KB
  float*     lws   = (float*)(ws2 + (30u << 20));

  prep_kernel<<<18792, 256, 0, stream>>>(P, Nn, Pf, Nf, w2, w3, w2t, w3t);

  sim_mfma_kernel<<<256, 512, 0, stream>>>(A, Pf, Nf, qm, pm, nm, sim);
  conv1_kernel<<<1024, 256, 0, stream>>>(sim, w1, b1, x1);
  conv2_mfma<<<dim3(16, 64), 256, 0, stream>>>(x1, w2t, b2w, x2);
  conv3_mfma<<<dim3(8, 64), 256, 0, stream>>>(x2, w3t, b3, wf, bf, shead);
  head_final_kernel<<<64, 256, 0, stream>>>(shead, qm, pm, nm, out, lws);
  loss_sum_kernel<<<1, 64, 0, stream>>>(lws, out);
}